// Round 8
// baseline (259.341 us; speedup 1.0000x reference)
//
#include <hip/hip_runtime.h>

// EOQLinear: int4-quantized GEMV.
//   out[n] = sum_b scales[n,b] * sum_{q in block b} w_int[n,q] * x[q]
// packed_w[n,j] is an int32 in [0,256): low nibble -> k=2j, high nibble -> k=2j+1,
// both offset by -8.
//
// DTYPE NOTE (round-1): harness stages the reference's float16 tensors as FLOAT32.
//
// ROUND-8: MEASUREMENT PROBE (deliberate regression). Rounds 2/6/7 all land at
// ~197-202 us despite a 4x per-wave-MLP restructure -> kernel time is either a
// small fraction of dur_us (harness restore+poison ~120 us is timed) or pinned
// at a shared ceiling; the kernel dispatch has never appeared in the rocprof
// top-5 (cutoff ~77.6 us), so its duration is < 77 us but otherwise unknown.
// This round runs the IDENTICAL dot product 4x (averaged, *0.25f exact) so the
// kernel exceeds the top-5 cutoff and exposes its own FETCH_SIZE / hbm_gbps /
// VALUBusy / Occupancy row. zeroOff (=0 at runtime) makes per-pass addresses
// opaque to the compiler so the repeated loads cannot be CSE'd.
// Interpretation plan:
//   FETCH ~520 MB @ ~6 TB/s, dur ~85 us  -> single-pass T~21 us: round-7 kernel
//       was already HBM-rooflined; revert and declare harness floor.
//   FETCH ~130 MB, dur ~T+40 us          -> L3 absorbs re-reads; T from delta.
//   BW << 6 TB/s, low VALUBusy/Occ       -> kernel genuinely slow; fix per counters.

#define ROWS_PER_WAVE 4
#define PASSES 4

__global__ __launch_bounds__(256, 2)
void eoq_gemv_kernel(const float* __restrict__ x,
                     const int* __restrict__ packed_w,
                     const float* __restrict__ scales,
                     float* __restrict__ out,
                     int N, int halfK, int iters, int sShift, int blocksPerRow,
                     int zeroOff)
{
    const int lane = threadIdx.x & 63;
    const int wave = threadIdx.x >> 6;
    const int row0 = (blockIdx.x * 4 + wave) * ROWS_PER_WAVE;
    if (row0 >= N) return;

    const float4* __restrict__ x4p = reinterpret_cast<const float4*>(x);

    const int4* w4p[ROWS_PER_WAVE];
    const float* srow[ROWS_PER_WAVE];
    #pragma unroll
    for (int r = 0; r < ROWS_PER_WAVE; ++r) {
        w4p[r]  = reinterpret_cast<const int4*>(packed_w + (size_t)(row0 + r) * halfK);
        srow[r] = scales + (size_t)(row0 + r) * blocksPerRow;
    }

    float acc[ROWS_PER_WAVE] = {0.f, 0.f, 0.f, 0.f};

    for (int pass = 0; pass < PASSES; ++pass) {
        // pass * zeroOff == 0 at runtime, but the compiler can't prove it ->
        // per-pass loads are distinct expressions, no CSE across passes.
        const int base = pass * zeroOff + lane;

        #pragma unroll 2
        for (int it = 0; it < iters; ++it) {
            const int j4 = (it << 6) + base;        // 16B-chunk index in the row
            const float4 xa = x4p[2 * j4];
            const float4 xb = x4p[2 * j4 + 1];
            const int    sIdx = j4 >> sShift;

            #pragma unroll
            for (int r = 0; r < ROWS_PER_WAVE; ++r) {
                const int4  w4 = w4p[r][j4];
                const float s  = srow[r][sIdx];

                const unsigned w0 = (unsigned)w4.x;
                const unsigned w1 = (unsigned)w4.y;
                const unsigned w2 = (unsigned)w4.z;
                const unsigned w3 = (unsigned)w4.w;

                float part = 0.f;
                part = fmaf((float)(int)(w0 & 0xFu) - 8.f, xa.x, part);
                part = fmaf((float)(int)(w0 >> 4)   - 8.f, xa.y, part);
                part = fmaf((float)(int)(w1 & 0xFu) - 8.f, xa.z, part);
                part = fmaf((float)(int)(w1 >> 4)   - 8.f, xa.w, part);
                part = fmaf((float)(int)(w2 & 0xFu) - 8.f, xb.x, part);
                part = fmaf((float)(int)(w2 >> 4)   - 8.f, xb.y, part);
                part = fmaf((float)(int)(w3 & 0xFu) - 8.f, xb.z, part);
                part = fmaf((float)(int)(w3 >> 4)   - 8.f, xb.w, part);
                acc[r] = fmaf(s, part, acc[r]);
            }
        }
    }

    // average the identical passes (exact: *2^-2), then wave-64 reduction
    #pragma unroll
    for (int r = 0; r < ROWS_PER_WAVE; ++r) {
        float a = acc[r] * (1.0f / PASSES);
        #pragma unroll
        for (int off = 32; off > 0; off >>= 1)
            a += __shfl_down(a, off, 64);
        if (lane == 0 && row0 + r < N) out[row0 + r] = a;
    }
}

extern "C" void kernel_launch(void* const* d_in, const int* in_sizes, int n_in,
                              void* d_out, int out_size, void* d_ws, size_t ws_size,
                              hipStream_t stream) {
    const float* x      = (const float*)d_in[0];
    const int*   pw     = (const int*)d_in[1];
    const float* scales = (const float*)d_in[2];
    float*       out    = (float*)d_out;

    const int K     = in_sizes[0];         // 8192
    const int halfK = K >> 1;              // 4096
    const int N     = in_sizes[1] / halfK; // 8192
    const int blocksPerRow = in_sizes[2] / N;    // K/QB = 64

    const int qhalf = halfK / blocksPerRow;      // QB/2 (pow2)
    int qhalfShift = 0;
    while ((1 << qhalfShift) < qhalf) ++qhalfShift;
    const int sShift = qhalfShift - 2;           // 16B-chunk idx -> qblock idx

    const int iters = halfK >> 8;                // 16 column chunks per row

    const int rowsPerBlock = 4 * ROWS_PER_WAVE;  // 16
    dim3 grid((N + rowsPerBlock - 1) / rowsPerBlock), block(256);
    eoq_gemv_kernel<<<grid, block, 0, stream>>>(x, pw, scales, out,
                                                N, halfK, iters, sShift, blocksPerRow,
                                                /*zeroOff=*/0);
}